// Round 5
// baseline (357.394 us; speedup 1.0000x reference)
//
#include <hip/hip_runtime.h>
#include <hip/hip_bf16.h>
#include <hip/hip_fp16.h>

#define LRELU_SLOPE 0.2f

__device__ __forceinline__ float lrelu(float x) { return x > 0.f ? x : LRELU_SLOPE * x; }

typedef __attribute__((ext_vector_type(8))) short short8;
typedef __attribute__((ext_vector_type(4))) float f32x4;

__device__ __forceinline__ unsigned short f2bf(float f) {
    unsigned u = __builtin_bit_cast(unsigned, f);
    u = (u + 0x7FFFu + ((u >> 16) & 1u)) >> 16;  // RNE
    return (unsigned short)u;
}
__device__ __forceinline__ float bf2f(unsigned short b) {
    unsigned u = ((unsigned)b) << 16;
    return __builtin_bit_cast(float, u);
}

// ---------------- W pre-pack body: fp32 [K][64] -> B-fragment bf16 hi/lo ----------------
template <int K>
__device__ __forceinline__ void packW_body(const float* __restrict__ W,
                                           unsigned short* __restrict__ Bhi,
                                           unsigned short* __restrict__ Blo,
                                           int blk, int t) {
    constexpr int NKC = K / 32;
    int g = blk * 256 + t;
    if (g >= 4 * NKC * 64) return;
    int lane = g & 63;
    int kc = (g >> 6) % NKC;
    int ct = g / (64 * NKC);
    int qd = lane >> 4, col = lane & 15;
    #pragma unroll
    for (int j = 0; j < 8; j++) {
        int k = kc * 32 + qd * 8 + j;
        float w = W[(size_t)k * 64 + ct * 16 + col];
        unsigned short h = f2bf(w);
        float rem = w - bf2f(h);
        Bhi[(size_t)g * 8 + j] = h;
        Blo[(size_t)g * 8 + j] = f2bf(rem);
    }
}

// ---------------- r14: fused prep — packW1 + packW2 + zero(deg,gcnt) ----------------
// (zero must complete before hist -> stays its own dispatch, can't join k2)
__global__ __launch_bounds__(256) void k_prep(const float* __restrict__ W1,
                                              unsigned short* __restrict__ b1hi, unsigned short* __restrict__ b1lo,
                                              const float* __restrict__ W2,
                                              unsigned short* __restrict__ b2hi, unsigned short* __restrict__ b2lo,
                                              int* __restrict__ deg, int* __restrict__ gcnt, int N) {
    int b = blockIdx.x;
    if (b < 8)  { packW_body<256>(W1, b1hi, b1lo, b, threadIdx.x); return; }       // 4*8*64 = 8 blocks exact
    if (b < 10) { packW_body<64>(W2, b2hi, b2lo, b - 8, threadIdx.x); return; }    // 4*2*64 = 2 blocks exact
    int i = (b - 10) * 256 + threadIdx.x;
    if (i < N) deg[i] = 0;
    if (i == 0) *gcnt = 0;
}

// ---------------- r14: offsets WITHOUT prefix scan ----------------
// Segment ORDER across nodes is irrelevant; wave-local scan + one atomicAdd per
// wave on a global counter. start[] for scatter, packed sd2[]={start,deg} for attn.
__global__ __launch_bounds__(256) void k_offsets(const int* __restrict__ deg, int* __restrict__ start,
                                                 int2* __restrict__ sd2, int* __restrict__ gcnt, int N) {
    int idx = blockIdx.x * 256 + threadIdx.x;
    int lane = threadIdx.x & 63;
    int v = (idx < N) ? deg[idx] : 0;
    int incl = v;
    #pragma unroll
    for (int d = 1; d < 64; d <<= 1) {
        int u = __shfl_up(incl, d);
        if (lane >= d) incl += u;
    }
    int total = __shfl(incl, 63);
    int base = 0;
    if (lane == 0) base = atomicAdd(gcnt, total);
    base = __shfl(base, 0);
    int st = base + incl - v;
    if (idx < N) {
        start[idx] = st;
        sd2[idx] = make_int2(st, v);
    }
}

// ---------------- MFMA GEMM body: XW(fp16) = X[N,K] @ W[K,64] + fused logits ----------------
// Split-precision bf16 (r10): 3 MFMAs (AhBh+AlBh+AhBl) => ~16-bit mantissa.
// r12: XW stored as fp16 — consumer is the gather; fp16 halves line footprint.
// r17: factored into a __device__ body so layer-1 halves can be fused into the
// hist/scatter dispatches (independent work -> overlap on one stream).
template <int K>
__device__ __forceinline__ void mfma_body(const float* __restrict__ X,
                                          const unsigned short* __restrict__ Bhi,
                                          const unsigned short* __restrict__ Blo,
                                          const float* __restrict__ a_s, const float* __restrict__ a_d,
                                          __half* __restrict__ XW, float* __restrict__ Ssrc,
                                          float* __restrict__ Sdst, int N, int blk) {
    constexpr int NKC = K / 32;
    int t = threadIdx.x, lane = t & 63, wid = t >> 6;
    int mtile = blk * 4 + wid;
    if (mtile * 16 >= N) return;
    int m0 = mtile * 16;
    int qd = lane >> 4, col = lane & 15;

    int rA = m0 + col;
    rA = rA < N ? rA : N - 1;
    const float* xrow = X + (size_t)rA * K + qd * 8;

    const short8* bh = (const short8*)Bhi;
    const short8* bl = (const short8*)Blo;

    f32x4 acc[4];
    #pragma unroll
    for (int ct = 0; ct < 4; ct++) acc[ct] = (f32x4){0.f, 0.f, 0.f, 0.f};

    #pragma clang loop unroll(disable)
    for (int kc = 0; kc < NKC; kc++) {
        const float* xp = xrow + kc * 32;
        float4 xa = *(const float4*)xp;
        float4 xb = *(const float4*)(xp + 4);
        float xv[8] = {xa.x, xa.y, xa.z, xa.w, xb.x, xb.y, xb.z, xb.w};
        short8 ah, al;
        #pragma unroll
        for (int j = 0; j < 8; j++) {
            unsigned short h = f2bf(xv[j]);
            ah[j] = (short)h;
            al[j] = (short)f2bf(xv[j] - bf2f(h));
        }
        #pragma unroll
        for (int ct = 0; ct < 4; ct++) {
            short8 wh = bh[(ct * NKC + kc) * 64 + lane];
            short8 wl = bl[(ct * NKC + kc) * 64 + lane];
            acc[ct] = __builtin_amdgcn_mfma_f32_16x16x32_bf16(ah, wh, acc[ct], 0, 0, 0);
            acc[ct] = __builtin_amdgcn_mfma_f32_16x16x32_bf16(al, wh, acc[ct], 0, 0, 0);
            acc[ct] = __builtin_amdgcn_mfma_f32_16x16x32_bf16(ah, wl, acc[ct], 0, 0, 0);
        }
    }

    float asx[4], adx[4];
    #pragma unroll
    for (int ct = 0; ct < 4; ct++) {
        asx[ct] = a_s[ct * 16 + col];
        adx[ct] = a_d[ct * 16 + col];
    }
    #pragma unroll
    for (int r = 0; r < 4; r++) {
        int row = m0 + qd * 4 + r;
        if (row < N) {
            float vs = 0.f, vd = 0.f;
            #pragma unroll
            for (int ct = 0; ct < 4; ct++) {
                float v = acc[ct][r];
                XW[(size_t)row * 64 + ct * 16 + col] = __float2half(v);
                vs += v * asx[ct];
                vd += v * adx[ct];
            }
            #pragma unroll
            for (int d = 1; d < 16; d <<= 1) {
                vs += __shfl_xor(vs, d);
                vd += __shfl_xor(vd, d);
            }
            if (col == 0) { Ssrc[row] = vs; Sdst[row] = vd; }
        }
    }
}

// ---------------- r17: hist ∥ mfma1a (independent; hist = long pole, goes first) ----------------
// r15 hist: the atomicAdd return value is the edge's rank within its dst segment.
__global__ __launch_bounds__(256) void k_hist_mfma(const int* __restrict__ dst, int* __restrict__ deg,
                                                   int* __restrict__ epos, int E, int histBlocks,
                                                   const float* __restrict__ X,
                                                   const unsigned short* __restrict__ Bhi,
                                                   const unsigned short* __restrict__ Blo,
                                                   const float* __restrict__ a_s, const float* __restrict__ a_d,
                                                   __half* __restrict__ XW, float* __restrict__ Ssrc,
                                                   float* __restrict__ Sdst, int N, int mfmaBase) {
    int b = blockIdx.x;
    if (b < histBlocks) {
        int i = b * 256 + threadIdx.x;
        if (i < E) epos[i] = atomicAdd(&deg[dst[i]], 1);
        return;
    }
    mfma_body<256>(X, Bhi, Blo, a_s, a_d, XW, Ssrc, Sdst, N, mfmaBase + (b - histBlocks));
}

// ---------------- r17: scatter ∥ mfma1b ----------------
// r15 scatter: atomic-free, csr[start[d] + rank] = src.
__global__ __launch_bounds__(256) void k_scatter_mfma(const int* __restrict__ src, const int* __restrict__ dst,
                                                      const int* __restrict__ start, const int* __restrict__ epos,
                                                      int* __restrict__ csr, int E, int scatBlocks,
                                                      const float* __restrict__ X,
                                                      const unsigned short* __restrict__ Bhi,
                                                      const unsigned short* __restrict__ Blo,
                                                      const float* __restrict__ a_s, const float* __restrict__ a_d,
                                                      __half* __restrict__ XW, float* __restrict__ Ssrc,
                                                      float* __restrict__ Sdst, int N, int mfmaBase) {
    int b = blockIdx.x;
    if (b < scatBlocks) {
        int i = b * 256 + threadIdx.x;
        if (i < E) csr[start[dst[i]] + epos[i]] = src[i];
        return;
    }
    mfma_body<256>(X, Bhi, Blo, a_s, a_d, XW, Ssrc, Sdst, N, mfmaBase + (b - scatBlocks));
}

// ---------------- layer-2 GEMM: standalone wrapper ----------------
template <int K>
__global__ __launch_bounds__(256) void k_mfma(const float* __restrict__ X,
                                              const unsigned short* __restrict__ Bhi,
                                              const unsigned short* __restrict__ Blo,
                                              const float* __restrict__ a_s, const float* __restrict__ a_d,
                                              __half* __restrict__ XW, float* __restrict__ Ssrc,
                                              float* __restrict__ Sdst, int N) {
    mfma_body<K>(X, Bhi, Blo, a_s, a_d, XW, Ssrc, Sdst, N, blockIdx.x);
}

// ---------------- attention + aggregate: FOUR nodes per wave (r16) ----------------
// 16 lanes per node (q=node slot, c=feature quad); wave count 25K; all 16 lanes
// carry the output row (no cross-group reduce). NO-MAX softmax (logits bounded
// ~8 over 2M edges; ratio identical up to ~1e-7 rel, tol 2^-9). Denom off the
// critical path; 4-shfl reduce in epilogue. First batch + self loads hoisted
// above the weight computation (latency hides under exp/lrelu).
__global__ __launch_bounds__(256) void k_attn(const __half* __restrict__ XW, const float* __restrict__ Ssrc,
                                              const float* __restrict__ Sdst, const int* __restrict__ csr,
                                              const int2* __restrict__ sd2,
                                              const float* __restrict__ bias, float* __restrict__ H,
                                              int N, int do_relu) {
    int t = threadIdx.x, lane = t & 63, wid = t >> 6;
    int q = lane >> 4;                        // node slot within wave
    int c = lane & 15;                        // feature quad
    int n = (blockIdx.x * 4 + wid) * 4 + q;   // 16 nodes per block
    bool valid = n < N;
    int nc = valid ? n : N - 1;               // clamp: compute garbage, never store

    int2 sv = sd2[nc];
    int st = sv.x, d = sv.y;
    float sd = Sdst[nc];
    int dcap = d < 16 ? d : 16;

    // edge slot: lane (q,c) holds edge c of node q (pad lanes -> row 0, weight 0)
    int myS = 0;
    if (c < d) myS = csr[st + c];

    // first-batch row indices (depend only on csr) -> issue loads before softmax
    int s0 = __shfl(myS, q * 16 + 0), s1 = __shfl(myS, q * 16 + 1);
    int s2 = __shfl(myS, q * 16 + 2), s3 = __shfl(myS, q * 16 + 3);
    float2 rs = *(const float2*)(XW + (size_t)nc * 64 + c * 4);
    float2 r0 = *(const float2*)(XW + (size_t)s0 * 64 + c * 4);
    float2 r1 = *(const float2*)(XW + (size_t)s1 * 64 + c * 4);
    float2 r2 = *(const float2*)(XW + (size_t)s2 * 64 + c * 4);
    float2 r3 = *(const float2*)(XW + (size_t)s3 * 64 + c * 4);

    // logits -> weights (no max subtraction)
    float wself = __expf(lrelu(Ssrc[nc] + sd));
    float myW = 0.f;
    if (c < d) myW = __expf(lrelu(Ssrc[myS] + sd));
    float dpart = myW + ((c == 0) ? wself : 0.f);

    float4 acc4 = make_float4(0.f, 0.f, 0.f, 0.f);
    auto accum = [&](float2 raw, float w) {
        const __half2* hp = (const __half2*)&raw;
        float2 f0 = __half22float2(hp[0]);
        float2 f1 = __half22float2(hp[1]);
        acc4.x += w * f0.x; acc4.y += w * f0.y; acc4.z += w * f1.x; acc4.w += w * f1.y;
    };

    float w0 = __shfl(myW, q * 16 + 0), w1 = __shfl(myW, q * 16 + 1);
    float w2 = __shfl(myW, q * 16 + 2), w3 = __shfl(myW, q * 16 + 3);
    accum(rs, wself);
    accum(r0, w0); accum(r1, w1); accum(r2, w2); accum(r3, w3);

    // remaining batches (deg > 4): 4 independent loads per round
    for (int i = 4; i < dcap; i += 4) {
        int t0 = __shfl(myS, q * 16 + i + 0), t1 = __shfl(myS, q * 16 + i + 1);
        int t2 = __shfl(myS, q * 16 + i + 2), t3 = __shfl(myS, q * 16 + i + 3);
        float2 q0 = *(const float2*)(XW + (size_t)t0 * 64 + c * 4);
        float2 q1 = *(const float2*)(XW + (size_t)t1 * 64 + c * 4);
        float2 q2 = *(const float2*)(XW + (size_t)t2 * 64 + c * 4);
        float2 q3 = *(const float2*)(XW + (size_t)t3 * 64 + c * 4);
        float v0 = __shfl(myW, q * 16 + i + 0), v1 = __shfl(myW, q * 16 + i + 1);
        float v2 = __shfl(myW, q * 16 + i + 2), v3 = __shfl(myW, q * 16 + i + 3);
        accum(q0, v0); accum(q1, v1); accum(q2, v2); accum(q3, v3);
    }

    // tail (deg > 16): ~2.7% of nodes; per-16-lane-group serial, all lanes carry row
    for (int i = 16; i < d; i++) {
        int s = csr[st + i];
        float w = __expf(lrelu(Ssrc[s] + sd));
        if (c == 0) dpart += w;
        float2 qv = *(const float2*)(XW + (size_t)s * 64 + c * 4);
        accum(qv, w);
    }

    // denom reduce within the 16-lane node group
    #pragma unroll
    for (int dd = 8; dd > 0; dd >>= 1) dpart += __shfl_xor(dpart, dd);

    if (valid) {
        float4 b4 = *(const float4*)&bias[c * 4];
        float inv = 1.f / dpart;
        float4 o;
        o.x = acc4.x * inv + b4.x;
        o.y = acc4.y * inv + b4.y;
        o.z = acc4.z * inv + b4.z;
        o.w = acc4.w * inv + b4.w;
        if (do_relu) {
            o.x = fmaxf(o.x, 0.f); o.y = fmaxf(o.y, 0.f);
            o.z = fmaxf(o.z, 0.f); o.w = fmaxf(o.w, 0.f);
        }
        *(float4*)&H[(size_t)n * 64 + c * 4] = o;
    }
}

// ---------------- head ----------------
__global__ __launch_bounds__(256) void k_head(const float* __restrict__ H, const int* __restrict__ ui,
                                              const int* __restrict__ mi, const float* __restrict__ fcW,
                                              const float* __restrict__ fcb, float* __restrict__ out, int B) {
    int t = threadIdx.x, lane = t & 63, wid = t >> 6;
    int i = blockIdx.x * 4 + wid;
    if (i >= B) return;
    int u = ui[i], m = mi[i];
    float v = H[(size_t)u * 64 + lane] * fcW[lane] + H[(size_t)m * 64 + lane] * fcW[64 + lane];
    #pragma unroll
    for (int dd = 32; dd > 0; dd >>= 1) v += __shfl_xor(v, dd);
    if (lane == 0) out[i] = v + fcb[0];
}

extern "C" void kernel_launch(void* const* d_in, const int* in_sizes, int n_in,
                              void* d_out, int out_size, void* d_ws, size_t ws_size,
                              hipStream_t stream) {
    const float* x   = (const float*)d_in[0];
    const int*   ei  = (const int*)d_in[1];
    const int*   ui  = (const int*)d_in[2];
    const int*   mi  = (const int*)d_in[3];
    const float* W1  = (const float*)d_in[4];
    const float* as1 = (const float*)d_in[5];
    const float* ad1 = (const float*)d_in[6];
    const float* b1  = (const float*)d_in[7];
    const float* W2  = (const float*)d_in[8];
    const float* as2 = (const float*)d_in[9];
    const float* ad2 = (const float*)d_in[10];
    const float* b2  = (const float*)d_in[11];
    const float* fcW = (const float*)d_in[12];
    const float* fcb = (const float*)d_in[13];
    float* out = (float*)d_out;

    const int Hdim = in_sizes[5];            // 64
    const int FIN  = in_sizes[4] / Hdim;     // 256
    const int N    = in_sizes[0] / FIN;      // 100000
    const int E    = in_sizes[1] / 2;        // 1000000
    const int B    = in_sizes[2];            // 16384

    char* w = (char*)d_ws;
    auto alloc = [&](size_t bytes) -> void* {
        void* p = (void*)w;
        w += (bytes + 255) & ~(size_t)255;
        return p;
    };
    __half* xw  = (__half*)alloc((size_t)N * 64 * 2);
    float* hbuf = (float*)alloc((size_t)N * 64 * 4);
    float* ssrc = (float*)alloc((size_t)N * 4);
    float* sdst = (float*)alloc((size_t)N * 4);
    int* deg    = (int*)alloc((size_t)N * 4);
    int* startv = (int*)alloc((size_t)N * 4);
    int2* sd2   = (int2*)alloc((size_t)N * 8);
    int* gcnt   = (int*)alloc(256);
    int* csr    = (int*)alloc((size_t)E * 4);
    int* epos   = (int*)alloc((size_t)E * 4);
    unsigned short* b1hi = (unsigned short*)alloc((size_t)4 * 8 * 64 * 8 * 2);
    unsigned short* b1lo = (unsigned short*)alloc((size_t)4 * 8 * 64 * 8 * 2);
    unsigned short* b2hi = (unsigned short*)alloc((size_t)4 * 2 * 64 * 8 * 2);
    unsigned short* b2lo = (unsigned short*)alloc((size_t)4 * 2 * 64 * 8 * 2);

    const int* esrc = ei;
    const int* edst = ei + E;

    const int mfmaBlocks = ((N + 15) / 16 + 3) / 4;   // 1563
    const int mfmaA = mfmaBlocks / 2;                  // layer-1 first half (with hist)
    const int mfmaB = mfmaBlocks - mfmaA;              // layer-1 second half (with scatter)
    const int histBlocks = (E + 255) / 256;            // 3907
    const int attnBlocks = (N + 15) / 16;

    // --- prep: packW1 + packW2 + zero(deg,gcnt) fused (zero must precede hist) ---
    int prepBlocks = 10 + (N + 255) / 256;
    k_prep<<<prepBlocks, 256, 0, stream>>>(W1, b1hi, b1lo, W2, b2hi, b2lo, deg, gcnt, N);

    // --- r17 overlap: CSR chain ∥ layer-1 GEMM halves ---
    k_hist_mfma<<<histBlocks + mfmaA, 256, 0, stream>>>(edst, deg, epos, E, histBlocks,
                                                        x, b1hi, b1lo, as1, ad1, xw, ssrc, sdst, N, 0);
    k_offsets<<<(N + 255) / 256, 256, 0, stream>>>(deg, startv, sd2, gcnt, N);
    k_scatter_mfma<<<histBlocks + mfmaB, 256, 0, stream>>>(esrc, edst, startv, epos, csr, E, histBlocks,
                                                           x, b1hi, b1lo, as1, ad1, xw, ssrc, sdst, N, mfmaA);

    // --- layer 1 attention ---
    k_attn<<<attnBlocks, 256, 0, stream>>>(xw, ssrc, sdst, csr, sd2, b1, hbuf, N, 1);

    // --- layer 2 ---
    k_mfma<64><<<mfmaBlocks, 256, 0, stream>>>(hbuf, b2hi, b2lo, as2, ad2, xw, ssrc, sdst, N);
    k_attn<<<attnBlocks, 256, 0, stream>>>(xw, ssrc, sdst, csr, sd2, b2, hbuf, N, 0);

    // --- head ---
    k_head<<<(B + 3) / 4, 256, 0, stream>>>(hbuf, ui, mi, fcW, fcb, out, B);
}

// Round 6
// 347.164 us; speedup vs baseline: 1.0295x; 1.0295x over previous
//
#include <hip/hip_runtime.h>
#include <hip/hip_bf16.h>
#include <hip/hip_fp16.h>

#define LRELU_SLOPE 0.2f
#define CSR_STRIDE 32

__device__ __forceinline__ float lrelu(float x) { return x > 0.f ? x : LRELU_SLOPE * x; }

typedef __attribute__((ext_vector_type(8))) short short8;
typedef __attribute__((ext_vector_type(4))) float f32x4;

__device__ __forceinline__ unsigned short f2bf(float f) {
    unsigned u = __builtin_bit_cast(unsigned, f);
    u = (u + 0x7FFFu + ((u >> 16) & 1u)) >> 16;  // RNE
    return (unsigned short)u;
}
__device__ __forceinline__ float bf2f(unsigned short b) {
    unsigned u = ((unsigned)b) << 16;
    return __builtin_bit_cast(float, u);
}

// ---------------- W pre-pack body: fp32 [K][64] -> B-fragment bf16 hi/lo ----------------
template <int K>
__device__ __forceinline__ void packW_body(const float* __restrict__ W,
                                           unsigned short* __restrict__ Bhi,
                                           unsigned short* __restrict__ Blo,
                                           int blk, int t) {
    constexpr int NKC = K / 32;
    int g = blk * 256 + t;
    if (g >= 4 * NKC * 64) return;
    int lane = g & 63;
    int kc = (g >> 6) % NKC;
    int ct = g / (64 * NKC);
    int qd = lane >> 4, col = lane & 15;
    #pragma unroll
    for (int j = 0; j < 8; j++) {
        int k = kc * 32 + qd * 8 + j;
        float w = W[(size_t)k * 64 + ct * 16 + col];
        unsigned short h = f2bf(w);
        float rem = w - bf2f(h);
        Bhi[(size_t)g * 8 + j] = h;
        Blo[(size_t)g * 8 + j] = f2bf(rem);
    }
}

// ---------------- fused prep — packW1 + packW2 + zero(deg,ovfCnt) ----------------
__global__ __launch_bounds__(256) void k_prep(const float* __restrict__ W1,
                                              unsigned short* __restrict__ b1hi, unsigned short* __restrict__ b1lo,
                                              const float* __restrict__ W2,
                                              unsigned short* __restrict__ b2hi, unsigned short* __restrict__ b2lo,
                                              int* __restrict__ deg, int* __restrict__ ovfCnt, int N) {
    int b = blockIdx.x;
    if (b < 8)  { packW_body<256>(W1, b1hi, b1lo, b, threadIdx.x); return; }       // 4*8*64 = 8 blocks exact
    if (b < 10) { packW_body<64>(W2, b2hi, b2lo, b - 8, threadIdx.x); return; }    // 4*2*64 = 2 blocks exact
    int i = (b - 10) * 256 + threadIdx.x;
    if (i < N) deg[i] = 0;
    if (i == 0) *ovfCnt = 0;
}

// ---------------- r18: single-pass CSR build (replaces hist + offsets + scatter) ----------------
// Fixed 32-slot bucket per node: csr[d*32 + rank] = src, rank from one atomicAdd.
// Deletes one full edge pass + 1M atomics + epos traffic + 2 dispatches (r14
// insight: segment placement is free). Each bucket = one 128B line, so a node's
// ~10 writes hit the same line. P(deg>32 | lambda~10) ~ 1e-9: overflow edges go
// to a device-append list scanned by attn only when nonempty (never, here —
// but correctness does not depend on that).
// r17 lesson: do NOT grid-fuse this atomic-latency kernel with MFMA work.
__global__ void k_build(const int* __restrict__ src, const int* __restrict__ dst,
                        int* __restrict__ deg, int* __restrict__ csr,
                        int* __restrict__ ovfCnt, int2* __restrict__ ovf, int E) {
    int i = blockIdx.x * blockDim.x + threadIdx.x;
    if (i >= E) return;
    int d = dst[i], s = src[i];
    int p = atomicAdd(&deg[d], 1);
    if (p < CSR_STRIDE) {
        csr[d * CSR_STRIDE + p] = s;
    } else {
        int o = atomicAdd(ovfCnt, 1);
        ovf[o] = make_int2(d, s);
    }
}

// ---------------- MFMA GEMM body: XW(fp16) = X[N,K] @ W[K,64] + fused logits ----------------
// Split-precision bf16 (r10): 3 MFMAs (AhBh+AlBh+AhBl) => ~16-bit mantissa.
// r12: XW stored as fp16 — consumer is the gather; fp16 halves line footprint.
// X-read memory-bound (~16µs floor at K=256). Standalone dispatch (r17 lesson).
template <int K>
__device__ __forceinline__ void mfma_body(const float* __restrict__ X,
                                          const unsigned short* __restrict__ Bhi,
                                          const unsigned short* __restrict__ Blo,
                                          const float* __restrict__ a_s, const float* __restrict__ a_d,
                                          __half* __restrict__ XW, float* __restrict__ Ssrc,
                                          float* __restrict__ Sdst, int N, int blk) {
    constexpr int NKC = K / 32;
    int t = threadIdx.x, lane = t & 63, wid = t >> 6;
    int mtile = blk * 4 + wid;
    if (mtile * 16 >= N) return;
    int m0 = mtile * 16;
    int qd = lane >> 4, col = lane & 15;

    int rA = m0 + col;
    rA = rA < N ? rA : N - 1;
    const float* xrow = X + (size_t)rA * K + qd * 8;

    const short8* bh = (const short8*)Bhi;
    const short8* bl = (const short8*)Blo;

    f32x4 acc[4];
    #pragma unroll
    for (int ct = 0; ct < 4; ct++) acc[ct] = (f32x4){0.f, 0.f, 0.f, 0.f};

    #pragma clang loop unroll(disable)
    for (int kc = 0; kc < NKC; kc++) {
        const float* xp = xrow + kc * 32;
        float4 xa = *(const float4*)xp;
        float4 xb = *(const float4*)(xp + 4);
        float xv[8] = {xa.x, xa.y, xa.z, xa.w, xb.x, xb.y, xb.z, xb.w};
        short8 ah, al;
        #pragma unroll
        for (int j = 0; j < 8; j++) {
            unsigned short h = f2bf(xv[j]);
            ah[j] = (short)h;
            al[j] = (short)f2bf(xv[j] - bf2f(h));
        }
        #pragma unroll
        for (int ct = 0; ct < 4; ct++) {
            short8 wh = bh[(ct * NKC + kc) * 64 + lane];
            short8 wl = bl[(ct * NKC + kc) * 64 + lane];
            acc[ct] = __builtin_amdgcn_mfma_f32_16x16x32_bf16(ah, wh, acc[ct], 0, 0, 0);
            acc[ct] = __builtin_amdgcn_mfma_f32_16x16x32_bf16(al, wh, acc[ct], 0, 0, 0);
            acc[ct] = __builtin_amdgcn_mfma_f32_16x16x32_bf16(ah, wl, acc[ct], 0, 0, 0);
        }
    }

    float asx[4], adx[4];
    #pragma unroll
    for (int ct = 0; ct < 4; ct++) {
        asx[ct] = a_s[ct * 16 + col];
        adx[ct] = a_d[ct * 16 + col];
    }
    #pragma unroll
    for (int r = 0; r < 4; r++) {
        int row = m0 + qd * 4 + r;
        if (row < N) {
            float vs = 0.f, vd = 0.f;
            #pragma unroll
            for (int ct = 0; ct < 4; ct++) {
                float v = acc[ct][r];
                XW[(size_t)row * 64 + ct * 16 + col] = __float2half(v);
                vs += v * asx[ct];
                vd += v * adx[ct];
            }
            #pragma unroll
            for (int d = 1; d < 16; d <<= 1) {
                vs += __shfl_xor(vs, d);
                vd += __shfl_xor(vd, d);
            }
            if (col == 0) { Ssrc[row] = vs; Sdst[row] = vd; }
        }
    }
}

template <int K>
__global__ __launch_bounds__(256) void k_mfma(const float* __restrict__ X,
                                              const unsigned short* __restrict__ Bhi,
                                              const unsigned short* __restrict__ Blo,
                                              const float* __restrict__ a_s, const float* __restrict__ a_d,
                                              __half* __restrict__ XW, float* __restrict__ Ssrc,
                                              float* __restrict__ Sdst, int N) {
    mfma_body<K>(X, Bhi, Blo, a_s, a_d, XW, Ssrc, Sdst, N, blockIdx.x);
}

// ---------------- attention + aggregate: FOUR nodes per wave (r16) ----------------
// 16 lanes per node (q=node slot, c=feature quad); all 16 lanes carry the output
// row (no cross-group reduce). NO-MAX softmax (logits bounded ~8 over 2M edges;
// ratio identical up to ~1e-7 rel, tol 2^-9). Denom off critical path; 4-shfl
// reduce in epilogue. First batch + self loads hoisted above weight computation.
// r18: fixed-stride CSR (st = n*32), deg[] 4B load (sd2 gone), tail capped at
// slot 32 + overflow-list scan (enters only if ovfCnt>0; expected 0).
__global__ __launch_bounds__(256) void k_attn(const __half* __restrict__ XW, const float* __restrict__ Ssrc,
                                              const float* __restrict__ Sdst, const int* __restrict__ csr,
                                              const int* __restrict__ deg,
                                              const int* __restrict__ ovfCnt, const int2* __restrict__ ovf,
                                              const float* __restrict__ bias, float* __restrict__ H,
                                              int N, int do_relu) {
    int t = threadIdx.x, lane = t & 63, wid = t >> 6;
    int q = lane >> 4;                        // node slot within wave
    int c = lane & 15;                        // feature quad
    int n = (blockIdx.x * 4 + wid) * 4 + q;   // 16 nodes per block
    bool valid = n < N;
    int nc = valid ? n : N - 1;               // clamp: compute garbage, never store

    int d = deg[nc];
    int st = nc * CSR_STRIDE;
    float sd = Sdst[nc];
    int d32 = d < CSR_STRIDE ? d : CSR_STRIDE;
    int dcap = d < 16 ? d : 16;

    // edge slot: lane (q,c) holds edge c of node q (pad lanes -> row 0, weight 0)
    int myS = 0;
    if (c < dcap) myS = csr[st + c];

    // first-batch row indices (depend only on csr) -> issue loads before softmax
    int s0 = __shfl(myS, q * 16 + 0), s1 = __shfl(myS, q * 16 + 1);
    int s2 = __shfl(myS, q * 16 + 2), s3 = __shfl(myS, q * 16 + 3);
    float2 rs = *(const float2*)(XW + (size_t)nc * 64 + c * 4);
    float2 r0 = *(const float2*)(XW + (size_t)s0 * 64 + c * 4);
    float2 r1 = *(const float2*)(XW + (size_t)s1 * 64 + c * 4);
    float2 r2 = *(const float2*)(XW + (size_t)s2 * 64 + c * 4);
    float2 r3 = *(const float2*)(XW + (size_t)s3 * 64 + c * 4);

    // logits -> weights (no max subtraction)
    float wself = __expf(lrelu(Ssrc[nc] + sd));
    float myW = 0.f;
    if (c < dcap) myW = __expf(lrelu(Ssrc[myS] + sd));
    float dpart = myW + ((c == 0) ? wself : 0.f);

    float4 acc4 = make_float4(0.f, 0.f, 0.f, 0.f);
    auto accum = [&](float2 raw, float w) {
        const __half2* hp = (const __half2*)&raw;
        float2 f0 = __half22float2(hp[0]);
        float2 f1 = __half22float2(hp[1]);
        acc4.x += w * f0.x; acc4.y += w * f0.y; acc4.z += w * f1.x; acc4.w += w * f1.y;
    };

    float w0 = __shfl(myW, q * 16 + 0), w1 = __shfl(myW, q * 16 + 1);
    float w2 = __shfl(myW, q * 16 + 2), w3 = __shfl(myW, q * 16 + 3);
    accum(rs, wself);
    accum(r0, w0); accum(r1, w1); accum(r2, w2); accum(r3, w3);

    // remaining batches (deg > 4): 4 independent loads per round
    for (int i = 4; i < dcap; i += 4) {
        int t0 = __shfl(myS, q * 16 + i + 0), t1 = __shfl(myS, q * 16 + i + 1);
        int t2 = __shfl(myS, q * 16 + i + 2), t3 = __shfl(myS, q * 16 + i + 3);
        float2 q0 = *(const float2*)(XW + (size_t)t0 * 64 + c * 4);
        float2 q1 = *(const float2*)(XW + (size_t)t1 * 64 + c * 4);
        float2 q2 = *(const float2*)(XW + (size_t)t2 * 64 + c * 4);
        float2 q3 = *(const float2*)(XW + (size_t)t3 * 64 + c * 4);
        float v0 = __shfl(myW, q * 16 + i + 0), v1 = __shfl(myW, q * 16 + i + 1);
        float v2 = __shfl(myW, q * 16 + i + 2), v3 = __shfl(myW, q * 16 + i + 3);
        accum(q0, v0); accum(q1, v1); accum(q2, v2); accum(q3, v3);
    }

    // tail (16 < deg <= 32): ~2.7% of nodes; per-16-lane-group serial
    for (int i = 16; i < d32; i++) {
        int s = csr[st + i];
        float w = __expf(lrelu(Ssrc[s] + sd));
        if (c == 0) dpart += w;
        float2 qv = *(const float2*)(XW + (size_t)s * 64 + c * 4);
        accum(qv, w);
    }

    // overflow edges (deg > 32): expected count 0; one uniform load + branch
    int nov = *ovfCnt;
    if (nov > 0) {
        for (int j = 0; j < nov; j++) {
            int2 e = ovf[j];
            if (e.x == nc) {
                float w = __expf(lrelu(Ssrc[e.y] + sd));
                if (c == 0) dpart += w;
                float2 qv = *(const float2*)(XW + (size_t)e.y * 64 + c * 4);
                accum(qv, w);
            }
        }
    }

    // denom reduce within the 16-lane node group
    #pragma unroll
    for (int dd = 8; dd > 0; dd >>= 1) dpart += __shfl_xor(dpart, dd);

    if (valid) {
        float4 b4 = *(const float4*)&bias[c * 4];
        float inv = 1.f / dpart;
        float4 o;
        o.x = acc4.x * inv + b4.x;
        o.y = acc4.y * inv + b4.y;
        o.z = acc4.z * inv + b4.z;
        o.w = acc4.w * inv + b4.w;
        if (do_relu) {
            o.x = fmaxf(o.x, 0.f); o.y = fmaxf(o.y, 0.f);
            o.z = fmaxf(o.z, 0.f); o.w = fmaxf(o.w, 0.f);
        }
        *(float4*)&H[(size_t)n * 64 + c * 4] = o;
    }
}

// ---------------- head ----------------
__global__ __launch_bounds__(256) void k_head(const float* __restrict__ H, const int* __restrict__ ui,
                                              const int* __restrict__ mi, const float* __restrict__ fcW,
                                              const float* __restrict__ fcb, float* __restrict__ out, int B) {
    int t = threadIdx.x, lane = t & 63, wid = t >> 6;
    int i = blockIdx.x * 4 + wid;
    if (i >= B) return;
    int u = ui[i], m = mi[i];
    float v = H[(size_t)u * 64 + lane] * fcW[lane] + H[(size_t)m * 64 + lane] * fcW[64 + lane];
    #pragma unroll
    for (int dd = 32; dd > 0; dd >>= 1) v += __shfl_xor(v, dd);
    if (lane == 0) out[i] = v + fcb[0];
}

extern "C" void kernel_launch(void* const* d_in, const int* in_sizes, int n_in,
                              void* d_out, int out_size, void* d_ws, size_t ws_size,
                              hipStream_t stream) {
    const float* x   = (const float*)d_in[0];
    const int*   ei  = (const int*)d_in[1];
    const int*   ui  = (const int*)d_in[2];
    const int*   mi  = (const int*)d_in[3];
    const float* W1  = (const float*)d_in[4];
    const float* as1 = (const float*)d_in[5];
    const float* ad1 = (const float*)d_in[6];
    const float* b1  = (const float*)d_in[7];
    const float* W2  = (const float*)d_in[8];
    const float* as2 = (const float*)d_in[9];
    const float* ad2 = (const float*)d_in[10];
    const float* b2  = (const float*)d_in[11];
    const float* fcW = (const float*)d_in[12];
    const float* fcb = (const float*)d_in[13];
    float* out = (float*)d_out;

    const int Hdim = in_sizes[5];            // 64
    const int FIN  = in_sizes[4] / Hdim;     // 256
    const int N    = in_sizes[0] / FIN;      // 100000
    const int E    = in_sizes[1] / 2;        // 1000000
    const int B    = in_sizes[2];            // 16384

    char* w = (char*)d_ws;
    auto alloc = [&](size_t bytes) -> void* {
        void* p = (void*)w;
        w += (bytes + 255) & ~(size_t)255;
        return p;
    };
    __half* xw  = (__half*)alloc((size_t)N * 64 * 2);
    float* hbuf = (float*)alloc((size_t)N * 64 * 4);
    float* ssrc = (float*)alloc((size_t)N * 4);
    float* sdst = (float*)alloc((size_t)N * 4);
    int* deg    = (int*)alloc((size_t)N * 4);
    int* csr    = (int*)alloc((size_t)N * CSR_STRIDE * 4);
    int* ovfCnt = (int*)alloc(256);
    int2* ovf   = (int2*)alloc((size_t)65536 * 8);
    unsigned short* b1hi = (unsigned short*)alloc((size_t)4 * 8 * 64 * 8 * 2);
    unsigned short* b1lo = (unsigned short*)alloc((size_t)4 * 8 * 64 * 8 * 2);
    unsigned short* b2hi = (unsigned short*)alloc((size_t)4 * 2 * 64 * 8 * 2);
    unsigned short* b2lo = (unsigned short*)alloc((size_t)4 * 2 * 64 * 8 * 2);

    const int* esrc = ei;
    const int* edst = ei + E;

    const int mfmaBlocks = ((N + 15) / 16 + 3) / 4;   // 1563
    const int attnBlocks = (N + 15) / 16;

    // --- prep: packW1 + packW2 + zero(deg,ovfCnt) fused ---
    int prepBlocks = 10 + (N + 255) / 256;
    k_prep<<<prepBlocks, 256, 0, stream>>>(W1, b1hi, b1lo, W2, b2hi, b2lo, deg, ovfCnt, N);

    // --- single-pass CSR build (fixed-stride buckets) ---
    k_build<<<(E + 255) / 256, 256, 0, stream>>>(esrc, edst, deg, csr, ovfCnt, ovf, E);

    // --- layer 1 ---
    k_mfma<256><<<mfmaBlocks, 256, 0, stream>>>(x, b1hi, b1lo, as1, ad1, xw, ssrc, sdst, N);
    k_attn<<<attnBlocks, 256, 0, stream>>>(xw, ssrc, sdst, csr, deg, ovfCnt, ovf, b1, hbuf, N, 1);

    // --- layer 2 ---
    k_mfma<64><<<mfmaBlocks, 256, 0, stream>>>(hbuf, b2hi, b2lo, as2, ad2, xw, ssrc, sdst, N);
    k_attn<<<attnBlocks, 256, 0, stream>>>(xw, ssrc, sdst, csr, deg, ovfCnt, ovf, b2, hbuf, N, 0);

    // --- head ---
    k_head<<<(B + 3) / 4, 256, 0, stream>>>(hbuf, ui, mi, fcW, fcb, out, B);
}

// Round 7
// 335.017 us; speedup vs baseline: 1.0668x; 1.0363x over previous
//
#include <hip/hip_runtime.h>
#include <hip/hip_bf16.h>
#include <hip/hip_fp16.h>

#define LRELU_SLOPE 0.2f
#define CSR_STRIDE 32

__device__ __forceinline__ float lrelu(float x) { return x > 0.f ? x : LRELU_SLOPE * x; }

typedef __attribute__((ext_vector_type(8))) short short8;
typedef __attribute__((ext_vector_type(4))) float f32x4;

__device__ __forceinline__ unsigned short f2bf(float f) {
    unsigned u = __builtin_bit_cast(unsigned, f);
    u = (u + 0x7FFFu + ((u >> 16) & 1u)) >> 16;  // RNE
    return (unsigned short)u;
}
__device__ __forceinline__ float bf2f(unsigned short b) {
    unsigned u = ((unsigned)b) << 16;
    return __builtin_bit_cast(float, u);
}

// ---------------- W pre-pack body: fp32 [K][64] -> B-fragment bf16 hi/lo ----------------
template <int K>
__device__ __forceinline__ void packW_body(const float* __restrict__ W,
                                           unsigned short* __restrict__ Bhi,
                                           unsigned short* __restrict__ Blo,
                                           int blk, int t) {
    constexpr int NKC = K / 32;
    int g = blk * 256 + t;
    if (g >= 4 * NKC * 64) return;
    int lane = g & 63;
    int kc = (g >> 6) % NKC;
    int ct = g / (64 * NKC);
    int qd = lane >> 4, col = lane & 15;
    #pragma unroll
    for (int j = 0; j < 8; j++) {
        int k = kc * 32 + qd * 8 + j;
        float w = W[(size_t)k * 64 + ct * 16 + col];
        unsigned short h = f2bf(w);
        float rem = w - bf2f(h);
        Bhi[(size_t)g * 8 + j] = h;
        Blo[(size_t)g * 8 + j] = f2bf(rem);
    }
}

// ---------------- fused prep — packW1 + packW2 + zero(deg,ovfCnt) ----------------
__global__ __launch_bounds__(256) void k_prep(const float* __restrict__ W1,
                                              unsigned short* __restrict__ b1hi, unsigned short* __restrict__ b1lo,
                                              const float* __restrict__ W2,
                                              unsigned short* __restrict__ b2hi, unsigned short* __restrict__ b2lo,
                                              int* __restrict__ deg, int* __restrict__ ovfCnt, int N) {
    int b = blockIdx.x;
    if (b < 8)  { packW_body<256>(W1, b1hi, b1lo, b, threadIdx.x); return; }       // 4*8*64 = 8 blocks exact
    if (b < 10) { packW_body<64>(W2, b2hi, b2lo, b - 8, threadIdx.x); return; }    // 4*2*64 = 2 blocks exact
    int i = (b - 10) * 256 + threadIdx.x;
    if (i < N) deg[i] = 0;
    if (i == 0) *ovfCnt = 0;
}

// ---------------- r19: single-pass CSR build with 4-way atomic MLP ----------------
// r18 post-mortem: 1 outstanding atomic/wave => latency-bound at 80µs (VALUBusy
// 0.4%, HBM 10%). Fix: 4 edges/thread, ALL FOUR atomicAdds issued into
// independent temps BEFORE any dependent use — first use of p0 waits vmcnt(3),
// atomics 1-3 stay in flight => 4x MLP on the ~800cy device-scope atomic round
// trip. (r14's regression was DEPENDENT atomic->store->atomic chains; this is
// the independent-issue form.) Stores are fire-and-forget after the waits.
// Fixed 32-slot bucket per node: csr[d*32 + rank]. P(deg>32 | lambda~10) ~1e-9;
// overflow appends to a device list scanned by attn only when nonempty.
// r17 lesson: do NOT grid-fuse this atomic-latency kernel with MFMA work.
__global__ void k_build(const int* __restrict__ src, const int* __restrict__ dst,
                        int* __restrict__ deg, int* __restrict__ csr,
                        int* __restrict__ ovfCnt, int2* __restrict__ ovf, int E) {
    int i = (blockIdx.x * blockDim.x + threadIdx.x) * 4;
    if (i + 3 < E) {
        int4 d4 = *(const int4*)(dst + i);
        int4 s4 = *(const int4*)(src + i);
        int p0 = atomicAdd(&deg[d4.x], 1);
        int p1 = atomicAdd(&deg[d4.y], 1);
        int p2 = atomicAdd(&deg[d4.z], 1);
        int p3 = atomicAdd(&deg[d4.w], 1);
        if (p0 < CSR_STRIDE) csr[d4.x * CSR_STRIDE + p0] = s4.x;
        else { int o = atomicAdd(ovfCnt, 1); ovf[o] = make_int2(d4.x, s4.x); }
        if (p1 < CSR_STRIDE) csr[d4.y * CSR_STRIDE + p1] = s4.y;
        else { int o = atomicAdd(ovfCnt, 1); ovf[o] = make_int2(d4.y, s4.y); }
        if (p2 < CSR_STRIDE) csr[d4.z * CSR_STRIDE + p2] = s4.z;
        else { int o = atomicAdd(ovfCnt, 1); ovf[o] = make_int2(d4.z, s4.z); }
        if (p3 < CSR_STRIDE) csr[d4.w * CSR_STRIDE + p3] = s4.w;
        else { int o = atomicAdd(ovfCnt, 1); ovf[o] = make_int2(d4.w, s4.w); }
    } else {
        for (int j = i; j < E; j++) {
            int d = dst[j], s = src[j];
            int p = atomicAdd(&deg[d], 1);
            if (p < CSR_STRIDE) csr[d * CSR_STRIDE + p] = s;
            else { int o = atomicAdd(ovfCnt, 1); ovf[o] = make_int2(d, s); }
        }
    }
}

// ---------------- MFMA GEMM body: XW(fp16) = X[N,K] @ W[K,64] + fused logits ----------------
// Split-precision bf16 (r10): 3 MFMAs (AhBh+AlBh+AhBl) => ~16-bit mantissa.
// r12: XW stored as fp16 — consumer is the gather; fp16 halves line footprint.
// X-read memory-bound (~16µs floor at K=256). Standalone dispatch (r17 lesson).
template <int K>
__device__ __forceinline__ void mfma_body(const float* __restrict__ X,
                                          const unsigned short* __restrict__ Bhi,
                                          const unsigned short* __restrict__ Blo,
                                          const float* __restrict__ a_s, const float* __restrict__ a_d,
                                          __half* __restrict__ XW, float* __restrict__ Ssrc,
                                          float* __restrict__ Sdst, int N, int blk) {
    constexpr int NKC = K / 32;
    int t = threadIdx.x, lane = t & 63, wid = t >> 6;
    int mtile = blk * 4 + wid;
    if (mtile * 16 >= N) return;
    int m0 = mtile * 16;
    int qd = lane >> 4, col = lane & 15;

    int rA = m0 + col;
    rA = rA < N ? rA : N - 1;
    const float* xrow = X + (size_t)rA * K + qd * 8;

    const short8* bh = (const short8*)Bhi;
    const short8* bl = (const short8*)Blo;

    f32x4 acc[4];
    #pragma unroll
    for (int ct = 0; ct < 4; ct++) acc[ct] = (f32x4){0.f, 0.f, 0.f, 0.f};

    #pragma clang loop unroll(disable)
    for (int kc = 0; kc < NKC; kc++) {
        const float* xp = xrow + kc * 32;
        float4 xa = *(const float4*)xp;
        float4 xb = *(const float4*)(xp + 4);
        float xv[8] = {xa.x, xa.y, xa.z, xa.w, xb.x, xb.y, xb.z, xb.w};
        short8 ah, al;
        #pragma unroll
        for (int j = 0; j < 8; j++) {
            unsigned short h = f2bf(xv[j]);
            ah[j] = (short)h;
            al[j] = (short)f2bf(xv[j] - bf2f(h));
        }
        #pragma unroll
        for (int ct = 0; ct < 4; ct++) {
            short8 wh = bh[(ct * NKC + kc) * 64 + lane];
            short8 wl = bl[(ct * NKC + kc) * 64 + lane];
            acc[ct] = __builtin_amdgcn_mfma_f32_16x16x32_bf16(ah, wh, acc[ct], 0, 0, 0);
            acc[ct] = __builtin_amdgcn_mfma_f32_16x16x32_bf16(al, wh, acc[ct], 0, 0, 0);
            acc[ct] = __builtin_amdgcn_mfma_f32_16x16x32_bf16(ah, wl, acc[ct], 0, 0, 0);
        }
    }

    float asx[4], adx[4];
    #pragma unroll
    for (int ct = 0; ct < 4; ct++) {
        asx[ct] = a_s[ct * 16 + col];
        adx[ct] = a_d[ct * 16 + col];
    }
    #pragma unroll
    for (int r = 0; r < 4; r++) {
        int row = m0 + qd * 4 + r;
        if (row < N) {
            float vs = 0.f, vd = 0.f;
            #pragma unroll
            for (int ct = 0; ct < 4; ct++) {
                float v = acc[ct][r];
                XW[(size_t)row * 64 + ct * 16 + col] = __float2half(v);
                vs += v * asx[ct];
                vd += v * adx[ct];
            }
            #pragma unroll
            for (int d = 1; d < 16; d <<= 1) {
                vs += __shfl_xor(vs, d);
                vd += __shfl_xor(vd, d);
            }
            if (col == 0) { Ssrc[row] = vs; Sdst[row] = vd; }
        }
    }
}

template <int K>
__global__ __launch_bounds__(256) void k_mfma(const float* __restrict__ X,
                                              const unsigned short* __restrict__ Bhi,
                                              const unsigned short* __restrict__ Blo,
                                              const float* __restrict__ a_s, const float* __restrict__ a_d,
                                              __half* __restrict__ XW, float* __restrict__ Ssrc,
                                              float* __restrict__ Sdst, int N) {
    mfma_body<K>(X, Bhi, Blo, a_s, a_d, XW, Ssrc, Sdst, N, blockIdx.x);
}

// ---------------- attention + aggregate: FOUR nodes per wave (r16) ----------------
// 16 lanes per node (q=node slot, c=feature quad); all 16 lanes carry the output
// row (no cross-group reduce). NO-MAX softmax (logits bounded ~8 over 2M edges;
// ratio identical up to ~1e-7 rel, tol 2^-9). Denom off critical path; 4-shfl
// reduce in epilogue. First batch + self loads hoisted above weight computation.
// r18: fixed-stride CSR (st = n*32), deg[] 4B load, tail capped at slot 32 +
// overflow-list scan (enters only if ovfCnt>0; expected 0).
__global__ __launch_bounds__(256) void k_attn(const __half* __restrict__ XW, const float* __restrict__ Ssrc,
                                              const float* __restrict__ Sdst, const int* __restrict__ csr,
                                              const int* __restrict__ deg,
                                              const int* __restrict__ ovfCnt, const int2* __restrict__ ovf,
                                              const float* __restrict__ bias, float* __restrict__ H,
                                              int N, int do_relu) {
    int t = threadIdx.x, lane = t & 63, wid = t >> 6;
    int q = lane >> 4;                        // node slot within wave
    int c = lane & 15;                        // feature quad
    int n = (blockIdx.x * 4 + wid) * 4 + q;   // 16 nodes per block
    bool valid = n < N;
    int nc = valid ? n : N - 1;               // clamp: compute garbage, never store

    int d = deg[nc];
    int st = nc * CSR_STRIDE;
    float sd = Sdst[nc];
    int d32 = d < CSR_STRIDE ? d : CSR_STRIDE;
    int dcap = d < 16 ? d : 16;

    // edge slot: lane (q,c) holds edge c of node q (pad lanes -> row 0, weight 0)
    int myS = 0;
    if (c < dcap) myS = csr[st + c];

    // first-batch row indices (depend only on csr) -> issue loads before softmax
    int s0 = __shfl(myS, q * 16 + 0), s1 = __shfl(myS, q * 16 + 1);
    int s2 = __shfl(myS, q * 16 + 2), s3 = __shfl(myS, q * 16 + 3);
    float2 rs = *(const float2*)(XW + (size_t)nc * 64 + c * 4);
    float2 r0 = *(const float2*)(XW + (size_t)s0 * 64 + c * 4);
    float2 r1 = *(const float2*)(XW + (size_t)s1 * 64 + c * 4);
    float2 r2 = *(const float2*)(XW + (size_t)s2 * 64 + c * 4);
    float2 r3 = *(const float2*)(XW + (size_t)s3 * 64 + c * 4);

    // logits -> weights (no max subtraction)
    float wself = __expf(lrelu(Ssrc[nc] + sd));
    float myW = 0.f;
    if (c < dcap) myW = __expf(lrelu(Ssrc[myS] + sd));
    float dpart = myW + ((c == 0) ? wself : 0.f);

    float4 acc4 = make_float4(0.f, 0.f, 0.f, 0.f);
    auto accum = [&](float2 raw, float w) {
        const __half2* hp = (const __half2*)&raw;
        float2 f0 = __half22float2(hp[0]);
        float2 f1 = __half22float2(hp[1]);
        acc4.x += w * f0.x; acc4.y += w * f0.y; acc4.z += w * f1.x; acc4.w += w * f1.y;
    };

    float w0 = __shfl(myW, q * 16 + 0), w1 = __shfl(myW, q * 16 + 1);
    float w2 = __shfl(myW, q * 16 + 2), w3 = __shfl(myW, q * 16 + 3);
    accum(rs, wself);
    accum(r0, w0); accum(r1, w1); accum(r2, w2); accum(r3, w3);

    // remaining batches (deg > 4): 4 independent loads per round
    for (int i = 4; i < dcap; i += 4) {
        int t0 = __shfl(myS, q * 16 + i + 0), t1 = __shfl(myS, q * 16 + i + 1);
        int t2 = __shfl(myS, q * 16 + i + 2), t3 = __shfl(myS, q * 16 + i + 3);
        float2 q0 = *(const float2*)(XW + (size_t)t0 * 64 + c * 4);
        float2 q1 = *(const float2*)(XW + (size_t)t1 * 64 + c * 4);
        float2 q2 = *(const float2*)(XW + (size_t)t2 * 64 + c * 4);
        float2 q3 = *(const float2*)(XW + (size_t)t3 * 64 + c * 4);
        float v0 = __shfl(myW, q * 16 + i + 0), v1 = __shfl(myW, q * 16 + i + 1);
        float v2 = __shfl(myW, q * 16 + i + 2), v3 = __shfl(myW, q * 16 + i + 3);
        accum(q0, v0); accum(q1, v1); accum(q2, v2); accum(q3, v3);
    }

    // tail (16 < deg <= 32): ~2.7% of nodes; per-16-lane-group serial
    for (int i = 16; i < d32; i++) {
        int s = csr[st + i];
        float w = __expf(lrelu(Ssrc[s] + sd));
        if (c == 0) dpart += w;
        float2 qv = *(const float2*)(XW + (size_t)s * 64 + c * 4);
        accum(qv, w);
    }

    // overflow edges (deg > 32): expected count 0; one uniform load + branch
    int nov = *ovfCnt;
    if (nov > 0) {
        for (int j = 0; j < nov; j++) {
            int2 e = ovf[j];
            if (e.x == nc) {
                float w = __expf(lrelu(Ssrc[e.y] + sd));
                if (c == 0) dpart += w;
                float2 qv = *(const float2*)(XW + (size_t)e.y * 64 + c * 4);
                accum(qv, w);
            }
        }
    }

    // denom reduce within the 16-lane node group
    #pragma unroll
    for (int dd = 8; dd > 0; dd >>= 1) dpart += __shfl_xor(dpart, dd);

    if (valid) {
        float4 b4 = *(const float4*)&bias[c * 4];
        float inv = 1.f / dpart;
        float4 o;
        o.x = acc4.x * inv + b4.x;
        o.y = acc4.y * inv + b4.y;
        o.z = acc4.z * inv + b4.z;
        o.w = acc4.w * inv + b4.w;
        if (do_relu) {
            o.x = fmaxf(o.x, 0.f); o.y = fmaxf(o.y, 0.f);
            o.z = fmaxf(o.z, 0.f); o.w = fmaxf(o.w, 0.f);
        }
        *(float4*)&H[(size_t)n * 64 + c * 4] = o;
    }
}

// ---------------- head ----------------
__global__ __launch_bounds__(256) void k_head(const float* __restrict__ H, const int* __restrict__ ui,
                                              const int* __restrict__ mi, const float* __restrict__ fcW,
                                              const float* __restrict__ fcb, float* __restrict__ out, int B) {
    int t = threadIdx.x, lane = t & 63, wid = t >> 6;
    int i = blockIdx.x * 4 + wid;
    if (i >= B) return;
    int u = ui[i], m = mi[i];
    float v = H[(size_t)u * 64 + lane] * fcW[lane] + H[(size_t)m * 64 + lane] * fcW[64 + lane];
    #pragma unroll
    for (int dd = 32; dd > 0; dd >>= 1) v += __shfl_xor(v, dd);
    if (lane == 0) out[i] = v + fcb[0];
}

extern "C" void kernel_launch(void* const* d_in, const int* in_sizes, int n_in,
                              void* d_out, int out_size, void* d_ws, size_t ws_size,
                              hipStream_t stream) {
    const float* x   = (const float*)d_in[0];
    const int*   ei  = (const int*)d_in[1];
    const int*   ui  = (const int*)d_in[2];
    const int*   mi  = (const int*)d_in[3];
    const float* W1  = (const float*)d_in[4];
    const float* as1 = (const float*)d_in[5];
    const float* ad1 = (const float*)d_in[6];
    const float* b1  = (const float*)d_in[7];
    const float* W2  = (const float*)d_in[8];
    const float* as2 = (const float*)d_in[9];
    const float* ad2 = (const float*)d_in[10];
    const float* b2  = (const float*)d_in[11];
    const float* fcW = (const float*)d_in[12];
    const float* fcb = (const float*)d_in[13];
    float* out = (float*)d_out;

    const int Hdim = in_sizes[5];            // 64
    const int FIN  = in_sizes[4] / Hdim;     // 256
    const int N    = in_sizes[0] / FIN;      // 100000
    const int E    = in_sizes[1] / 2;        // 1000000
    const int B    = in_sizes[2];            // 16384

    char* w = (char*)d_ws;
    auto alloc = [&](size_t bytes) -> void* {
        void* p = (void*)w;
        w += (bytes + 255) & ~(size_t)255;
        return p;
    };
    __half* xw  = (__half*)alloc((size_t)N * 64 * 2);
    float* hbuf = (float*)alloc((size_t)N * 64 * 4);
    float* ssrc = (float*)alloc((size_t)N * 4);
    float* sdst = (float*)alloc((size_t)N * 4);
    int* deg    = (int*)alloc((size_t)N * 4);
    int* csr    = (int*)alloc((size_t)N * CSR_STRIDE * 4);
    int* ovfCnt = (int*)alloc(256);
    int2* ovf   = (int2*)alloc((size_t)65536 * 8);
    unsigned short* b1hi = (unsigned short*)alloc((size_t)4 * 8 * 64 * 8 * 2);
    unsigned short* b1lo = (unsigned short*)alloc((size_t)4 * 8 * 64 * 8 * 2);
    unsigned short* b2hi = (unsigned short*)alloc((size_t)4 * 2 * 64 * 8 * 2);
    unsigned short* b2lo = (unsigned short*)alloc((size_t)4 * 2 * 64 * 8 * 2);

    const int* esrc = ei;
    const int* edst = ei + E;

    const int mfmaBlocks = ((N + 15) / 16 + 3) / 4;   // 1563
    const int attnBlocks = (N + 15) / 16;

    // --- prep: packW1 + packW2 + zero(deg,ovfCnt) fused ---
    int prepBlocks = 10 + (N + 255) / 256;
    k_prep<<<prepBlocks, 256, 0, stream>>>(W1, b1hi, b1lo, W2, b2hi, b2lo, deg, ovfCnt, N);

    // --- single-pass CSR build (fixed-stride buckets, 4-way atomic MLP) ---
    k_build<<<(E / 4 + 255) / 256, 256, 0, stream>>>(esrc, edst, deg, csr, ovfCnt, ovf, E);

    // --- layer 1 ---
    k_mfma<256><<<mfmaBlocks, 256, 0, stream>>>(x, b1hi, b1lo, as1, ad1, xw, ssrc, sdst, N);
    k_attn<<<attnBlocks, 256, 0, stream>>>(xw, ssrc, sdst, csr, deg, ovfCnt, ovf, b1, hbuf, N, 1);

    // --- layer 2 ---
    k_mfma<64><<<mfmaBlocks, 256, 0, stream>>>(hbuf, b2hi, b2lo, as2, ad2, xw, ssrc, sdst, N);
    k_attn<<<attnBlocks, 256, 0, stream>>>(xw, ssrc, sdst, csr, deg, ovfCnt, ovf, b2, hbuf, N, 0);

    // --- head ---
    k_head<<<(B + 3) / 4, 256, 0, stream>>>(hbuf, ui, mi, fcW, fcb, out, B);
}